// Round 12
// baseline (98.946 us; speedup 1.0000x reference)
//
#include <hip/hip_runtime.h>
#include <math.h>

#define DEV static __device__ __forceinline__

constexpr int SS = 12;
constexpr int NN = 207;
constexpr int NCIRC = 64 * NN;          // 13248 circuits
constexpr int NPAIR = NCIRC / 2;        // 6624 waves; circuit A = lanes 0-31, B = lanes 32-63
// pair (g, g+6624): same node -> shared adjacency mask, conv matrices,
// w1/w2 rows; both circuits share ONE instruction stream.

// Layout: 32 lanes/circuit, 8 amps/lane (NAMED v2f a0..a7, re/im packed).
// Amp bits 0,1,2 = in-lane "K slots"; amp bits 3..7 = lane bits 0..4;
// lane bit 5 = circuit selector. Qubit q starts at amp bit (7-q).
//
// HARD RULE (R2/R3 LDS-demotion, R8 scratch-spill): state must be NAMED
// SCALARS; runtime permutes via wave-uniform switch over named temps.
// R12: the adjacency permutation is folded ANALYTICALLY into the product-
// state construction (it permutes a product state -> select XOR-flipped
// trig factors per control bit) -- the 16-bperm gather stage is gone.

typedef float v2f __attribute__((ext_vector_type(2)));
typedef float v4f __attribute__((ext_vector_type(4)));

DEV v2f splat2(float x) { v2f r; r.x = x; r.y = x; return r; }
DEV v2f vfma(float m, v2f a, v2f acc) { return __builtin_elementwise_fma(splat2(m), a, acc); }
DEV v2f vmul(float m, v2f a) { return splat2(m) * a; }
template<int M> DEV float sxc(float v) { return __shfl_xor(v, M, 64); }
template<int M> DEV v2f sx2(v2f v) { v2f r; r.x = sxc<M>(v.x); r.y = sxc<M>(v.y); return r; }
DEV float bperm(int addr, float v) {
    return __int_as_float(__builtin_amdgcn_ds_bpermute(addr, __float_as_int(v)));
}

// real 4x4 matrix on 4 named slots (basis order b00,b01,b10,b11)
#define CONV4(P, x00, x01, x10, x11) do {                                  \
    v2f _b00 = x00, _b01 = x01, _b10 = x10, _b11 = x11;                    \
    x00 = vfma((P)[0],  _b00, vfma((P)[1],  _b01, vfma((P)[2],  _b10, vmul((P)[3],  _b11)))); \
    x01 = vfma((P)[4],  _b00, vfma((P)[5],  _b01, vfma((P)[6],  _b10, vmul((P)[7],  _b11)))); \
    x10 = vfma((P)[8],  _b00, vfma((P)[9],  _b01, vfma((P)[10], _b10, vmul((P)[11], _b11)))); \
    x11 = vfma((P)[12], _b00, vfma((P)[13], _b01, vfma((P)[14], _b10, vmul((P)[15], _b11)))); \
} while (0)

// conv on K bits; CONVM10 hi=k1,lo=k0; CONVM02 hi=k0,lo=k2; CONVM21 hi=k2,lo=k1
#define CONVM10(P) do { CONV4(P, a0, a1, a2, a3); CONV4(P, a4, a5, a6, a7); } while (0)
#define CONVM02(P) do { CONV4(P, a0, a4, a1, a5); CONV4(P, a2, a6, a3, a7); } while (0)
#define CONVM21(P) do { CONV4(P, a0, a2, a4, a6); CONV4(P, a1, a3, a5, a7); } while (0)

// half-shuffle swap of one (lo,hi) slot pair across lane bit LB
#define SWP(ML, lb, lo, hi) do {                                           \
    v2f _u = (lb) ? lo : hi;                                               \
    v2f _v = sx2<ML>(_u);                                                  \
    lo = (lb) ? _v : lo;                                                   \
    hi = (lb) ? hi : _v;                                                   \
} while (0)

#define SWKL0(LB) do { const bool _lb = (lane >> (LB)) & 1;                \
    SWP(1 << (LB), _lb, a0, a1); SWP(1 << (LB), _lb, a2, a3);              \
    SWP(1 << (LB), _lb, a4, a5); SWP(1 << (LB), _lb, a6, a7); } while (0)
#define SWKL1(LB) do { const bool _lb = (lane >> (LB)) & 1;                \
    SWP(1 << (LB), _lb, a0, a2); SWP(1 << (LB), _lb, a1, a3);              \
    SWP(1 << (LB), _lb, a4, a6); SWP(1 << (LB), _lb, a5, a7); } while (0)
#define SWKL2(LB) do { const bool _lb = (lane >> (LB)) & 1;                \
    SWP(1 << (LB), _lb, a0, a4); SWP(1 << (LB), _lb, a1, a5);              \
    SWP(1 << (LB), _lb, a2, a6); SWP(1 << (LB), _lb, a3, a7); } while (0)

// WHT butterfly stage (R7-verified)
template<int MK> DEV float whts(float p, int lane) {
    float t = sxc<MK>(p);
    return (lane & MK) ? (t - p) : (p + t);
}

// ---- prep kernel: blocks 0..51 = per-circuit front-end; block 52 = matrices
// + adjacency masks (identical to R11, verified). ----
__global__ void prep_kernel(const float* __restrict__ x, const float* __restrict__ adj,
                            const float* __restrict__ w_proj, const float* __restrict__ b_proj,
                            const float* __restrict__ qp, float* __restrict__ ws) {
    if (blockIdx.x < 52) {
        const int t = blockIdx.x * 256 + threadIdx.x;
        if (t >= NCIRC) return;
        const int b = t / NN, node = t - b * NN;
        const float* xp = x + ((size_t)b * SS * NN + node) * 2;
        v2f av0 = splat2(0.0f), av1 = av0, av2 = av0, av3 = av0,
            av4 = av0, av5 = av0, av6 = av0, av7 = av0;
#pragma unroll
        for (int s = 0; s < SS; s++) {
            const v2f xv = *(const v2f*)(xp + (size_t)s * (NN * 2));
            const float* wp = w_proj + 2 * s;
            av0 = __builtin_elementwise_fma(xv, *(const v2f*)(wp + 0 * 24), av0);
            av1 = __builtin_elementwise_fma(xv, *(const v2f*)(wp + 1 * 24), av1);
            av2 = __builtin_elementwise_fma(xv, *(const v2f*)(wp + 2 * 24), av2);
            av3 = __builtin_elementwise_fma(xv, *(const v2f*)(wp + 3 * 24), av3);
            av4 = __builtin_elementwise_fma(xv, *(const v2f*)(wp + 4 * 24), av4);
            av5 = __builtin_elementwise_fma(xv, *(const v2f*)(wp + 5 * 24), av5);
            av6 = __builtin_elementwise_fma(xv, *(const v2f*)(wp + 6 * 24), av6);
            av7 = __builtin_elementwise_fma(xv, *(const v2f*)(wp + 7 * 24), av7);
        }
        const float PI_F = 3.14159265358979323846f;
        const float ang0 = fminf(fmaxf(av0.x + av0.y + b_proj[0], -PI_F), PI_F);
        const float ang1 = fminf(fmaxf(av1.x + av1.y + b_proj[1], -PI_F), PI_F);
        const float ang2 = fminf(fmaxf(av2.x + av2.y + b_proj[2], -PI_F), PI_F);
        const float ang3 = fminf(fmaxf(av3.x + av3.y + b_proj[3], -PI_F), PI_F);
        const float ang4 = fminf(fmaxf(av4.x + av4.y + b_proj[4], -PI_F), PI_F);
        const float ang5 = fminf(fmaxf(av5.x + av5.y + b_proj[5], -PI_F), PI_F);
        const float ang6 = fminf(fmaxf(av6.x + av6.y + b_proj[6], -PI_F), PI_F);
        const float ang7 = fminf(fmaxf(av7.x + av7.y + b_proj[7], -PI_F), PI_F);
        float c0,s0,c1,s1,c2,s2,c3,s3,c4,s4,c5,s5,c6,s6,c7,s7;
        __sincosf(0.5f * ang0, &s0, &c0); __sincosf(0.5f * ang1, &s1, &c1);
        __sincosf(0.5f * ang2, &s2, &c2); __sincosf(0.5f * ang3, &s3, &c3);
        __sincosf(0.5f * ang4, &s4, &c4); __sincosf(0.5f * ang5, &s5, &c5);
        __sincosf(0.5f * ang6, &s6, &c6); __sincosf(0.5f * ang7, &s7, &c7);
        float* dst = ws + 256 + (size_t)t * 24;
        dst[0] = c0;  dst[1] = c1;  dst[2] = c2;  dst[3] = c3;
        dst[4] = c4;  dst[5] = c5;  dst[6] = c6;  dst[7] = c7;
        dst[8] = s0;  dst[9] = s1;  dst[10] = s2; dst[11] = s3;
        dst[12] = s4; dst[13] = s5; dst[14] = s6; dst[15] = s7;
        dst[16] = ang4; dst[17] = ang5; dst[18] = ang6; dst[19] = ang7;
        return;
    }
    // ---- block 52: adjacency masks + fused conv matrices ----
    const int n = threadIdx.x;
    if (n >= 14 && n < 64 + 14) {
        const int cq = n - 14;
        if (cq < 8) {
            int M = 0;
            for (int t = 0; t < 8; t++) {
                if (t != cq && adj[cq * NN + t] > 0.0f) M |= 1 << (7 - t);
            }
            ((int*)ws)[224 + cq] = M;
        }
        return;
    }
    if (n >= 14) return;
    // schedule: L1 (6,7)(4,5)(5,6)(2,3)(3,4)(0,1)(1,2); L2 (0,1)(2,3)(1,2)(4,5)(3,4)(6,7)(5,6)
    const int Jt[14] = {12, 8, 24, 4, 20, 0, 16, 28, 32, 44, 36, 48, 40, 52};
    const int J = Jt[n];
    float cg[4], sg[4];
    for (int i = 0; i < 4; i++) sincosf(0.5f * qp[J + i], &sg[i], &cg[i]);
    float A[16], B[16], M[16];
    {
        float H[2][2] = {{cg[0], -sg[0]}, {sg[0], cg[0]}};
        float L[2][2] = {{cg[1], -sg[1]}, {sg[1], cg[1]}};
        for (int a_ = 0; a_ < 2; a_++) for (int b_ = 0; b_ < 2; b_++)
            for (int p = 0; p < 2; p++) for (int q = 0; q < 2; q++)
                A[(2*a_+b_)*4 + (2*p+q)] = H[a_][p] * L[b_][q];
    }
    for (int j = 0; j < 4; j++) { float t = A[8+j]; A[8+j] = A[12+j]; A[12+j] = t; }  // CNOT hi->lo
    {
        float H[2][2] = {{cg[2], -sg[2]}, {sg[2], cg[2]}};
        float L[2][2] = {{cg[3], -sg[3]}, {sg[3], cg[3]}};
        for (int a_ = 0; a_ < 2; a_++) for (int b_ = 0; b_ < 2; b_++)
            for (int p = 0; p < 2; p++) for (int q = 0; q < 2; q++)
                B[(2*a_+b_)*4 + (2*p+q)] = H[a_][p] * L[b_][q];
    }
    for (int r = 0; r < 4; r++)
        for (int c = 0; c < 4; c++) {
            float acc = 0.0f;
            for (int k = 0; k < 4; k++) acc += B[r*4+k] * A[k*4+c];
            M[r*4+c] = acc;
        }
    for (int j = 0; j < 4; j++) { float t = M[4+j]; M[4+j] = M[12+j]; M[12+j] = t; }  // CNOT lo->hi
    // fold pool RYs (left-multiply; applied AFTER the conv) — R10-verified
    int mode = 0; float fc = 1.0f, fs = 0.0f;
    if (n == 7)  { sincosf(0.5f * qp[56], &fs, &fc); mode = 2; }   // RY(q0) on hi
    if (n == 9)  { sincosf(0.5f * qp[58], &fs, &fc); mode = 1; }   // RY(q2) on lo
    if (n == 11) { sincosf(0.5f * qp[60], &fs, &fc); mode = 1; }   // RY(q4) on lo
    if (n == 13) { sincosf(0.5f * qp[62], &fs, &fc); mode = 1; }   // RY(q6) on lo
    if (mode == 1) {
        for (int j = 0; j < 4; j++) {
            float r0 = M[j],     r1 = M[4+j];
            M[j]    = fc * r0 - fs * r1;  M[4+j]  = fs * r0 + fc * r1;
            float r2 = M[8+j],   r3 = M[12+j];
            M[8+j]  = fc * r2 - fs * r3;  M[12+j] = fs * r2 + fc * r3;
        }
    } else if (mode == 2) {
        for (int j = 0; j < 4; j++) {
            float r0 = M[j],     r2 = M[8+j];
            M[j]    = fc * r0 - fs * r2;  M[8+j]  = fs * r0 + fc * r2;
            float r1 = M[4+j],   r3 = M[12+j];
            M[4+j]  = fc * r1 - fs * r3;  M[12+j] = fs * r1 + fc * r3;
        }
    }
    for (int i = 0; i < 16; i++) ws[16*n + i] = M[i];
}

__global__ __launch_bounds__(256, 7) void qcnn_kernel(
    const float* __restrict__ ws,
    const float* __restrict__ w1, const float* __restrict__ b1,
    const float* __restrict__ w2, const float* __restrict__ b2,
    const float* __restrict__ w3, const float* __restrict__ b3,
    float* __restrict__ out)
{
    const int lane = threadIdx.x & 63;
    const int half = lane >> 5;                  // 0 = circuit A, 1 = circuit B
    const int hl   = lane & 31;
    const int wv   = threadIdx.x >> 6;
    const int gA   = blockIdx.x * 4 + wv;        // grid exact: 1656*4 == 6624
    const int bA   = gA / NN;
    const int node = gA - bA * NN;
    const int g    = gA + half * NPAIR;          // this half's circuit id

    // ---- load precomputed per-circuit trig (broadcast within each half) ----
    const float* cd = ws + 256 + (size_t)g * 24;
    const v4f cA = *(const v4f*)(cd + 0);        // c0..c3
    const v4f cB = *(const v4f*)(cd + 4);        // c4..c7
    const v4f sA = *(const v4f*)(cd + 8);        // s0..s3
    const v4f sB = *(const v4f*)(cd + 12);       // s4..s7
    const v4f rz = *(const v4f*)(cd + 16);       // clipped ang4..ang7

    // ---- adjacency fold: permuted product state built analytically ----
    const int cq  = node & 7;
    const int M   = ((const int*)ws)[224 + cq];
    const int Mlo = M & 7;                       // in-lane amp bits
    const int Mhi = (M >> 3) & 31;               // lane bits
    const int lx  = lane ^ Mhi;                  // XOR-flipped lane bits
    const int pc  = 7 - cq;                      // control amplitude bit

    // lane-factor products (qubits 0..4 -> lane bits 4..0), normal + flipped
    const float A1 = (((lane >> 4) & 1) ? sA.x : cA.x) * (((lane >> 3) & 1) ? sA.y : cA.y)
                   * (((lane >> 2) & 1) ? sA.z : cA.z) * (((lane >> 1) & 1) ? sA.w : cA.w)
                   * (((lane >> 0) & 1) ? sB.x : cB.x);
    const float A2 = (((lx >> 4) & 1) ? sA.x : cA.x) * (((lx >> 3) & 1) ? sA.y : cA.y)
                   * (((lx >> 2) & 1) ? sA.z : cA.z) * (((lx >> 1) & 1) ? sA.w : cA.w)
                   * (((lx >> 0) & 1) ? sB.x : cB.x);
    // RZ phases (qubits 0..3 -> lane bits 4..1), normal + flipped
    const float ph1 = (((lane >> 4) & 1) ? 0.5f : -0.5f) * rz.x
                    + (((lane >> 3) & 1) ? 0.5f : -0.5f) * rz.y
                    + (((lane >> 2) & 1) ? 0.5f : -0.5f) * rz.z
                    + (((lane >> 1) & 1) ? 0.5f : -0.5f) * rz.w;
    const float ph2 = (((lx >> 4) & 1) ? 0.5f : -0.5f) * rz.x
                    + (((lx >> 3) & 1) ? 0.5f : -0.5f) * rz.y
                    + (((lx >> 2) & 1) ? 0.5f : -0.5f) * rz.z
                    + (((lx >> 1) & 1) ? 0.5f : -0.5f) * rz.w;

    // in-lane coefficient products (amp bit0=q7, bit1=q6, bit2=q5)
    const float c5c6 = cB.y * cB.z, c5s6 = cB.y * sB.z;
    const float s5c6 = sB.y * cB.z, s5s6 = sB.y * sB.z;
    const float K0 = c5c6 * cB.w, K1 = c5c6 * sB.w;
    const float K2 = c5s6 * cB.w, K3 = c5s6 * sB.w;
    const float K4 = s5c6 * cB.w, K5 = s5c6 * sB.w;
    const float K6 = s5s6 * cB.w, K7 = s5s6 * sB.w;
    // KS_k = K_{k ^ Mlo} (wave-uniform switch over named scalars)
    float KS0, KS1, KS2, KS3, KS4, KS5, KS6, KS7;
    switch (Mlo) {
    case 0: KS0=K0;KS1=K1;KS2=K2;KS3=K3;KS4=K4;KS5=K5;KS6=K6;KS7=K7; break;
    case 1: KS0=K1;KS1=K0;KS2=K3;KS3=K2;KS4=K5;KS5=K4;KS6=K7;KS7=K6; break;
    case 2: KS0=K2;KS1=K3;KS2=K0;KS3=K1;KS4=K6;KS5=K7;KS6=K4;KS7=K5; break;
    case 3: KS0=K3;KS1=K2;KS2=K1;KS3=K0;KS4=K7;KS5=K6;KS6=K5;KS7=K4; break;
    case 4: KS0=K4;KS1=K5;KS2=K6;KS3=K7;KS4=K0;KS5=K1;KS6=K2;KS7=K3; break;
    case 5: KS0=K5;KS1=K4;KS2=K7;KS3=K6;KS4=K1;KS5=K0;KS6=K3;KS7=K2; break;
    case 6: KS0=K6;KS1=K7;KS2=K4;KS3=K5;KS4=K2;KS5=K3;KS6=K0;KS7=K1; break;
    default:KS0=K7;KS1=K6;KS2=K5;KS3=K4;KS4=K3;KS5=K2;KS6=K1;KS7=K0; break;
    }

    v2f a0, a1, a2, a3, a4, a5, a6, a7;
    if (pc >= 3) {
        // control is a lane bit: per-lane select of (A, phi, K-set)
        const bool ct = (lane >> (pc - 3)) & 1;
        const float Aef = ct ? A2 : A1;
        const float pef = ct ? ph2 : ph1;
        float cp, sp;
        __sincosf(pef, &sp, &cp);
        v2f ph; ph.x = cp; ph.y = sp;
        a0 = vmul(Aef * (ct ? KS0 : K0), ph);
        a1 = vmul(Aef * (ct ? KS1 : K1), ph);
        a2 = vmul(Aef * (ct ? KS2 : K2), ph);
        a3 = vmul(Aef * (ct ? KS3 : K3), ph);
        a4 = vmul(Aef * (ct ? KS4 : K4), ph);
        a5 = vmul(Aef * (ct ? KS5 : K5), ph);
        a6 = vmul(Aef * (ct ? KS6 : K6), ph);
        a7 = vmul(Aef * (ct ? KS7 : K7), ph);
    } else {
        // control is a reg bit: compile-time pattern per uniform pc case
        float cp, sp, cp2, sp2;
        __sincosf(ph1, &sp, &cp);
        __sincosf(ph2, &sp2, &cp2);
        v2f ph; ph.x = cp; ph.y = sp;
        v2f phf; phf.x = cp2; phf.y = sp2;
        if (pc == 2) {           // regs 4..7 permuted
            a0 = vmul(A1 * K0, ph);  a1 = vmul(A1 * K1, ph);
            a2 = vmul(A1 * K2, ph);  a3 = vmul(A1 * K3, ph);
            a4 = vmul(A2 * KS4, phf); a5 = vmul(A2 * KS5, phf);
            a6 = vmul(A2 * KS6, phf); a7 = vmul(A2 * KS7, phf);
        } else if (pc == 1) {    // regs 2,3,6,7 permuted
            a0 = vmul(A1 * K0, ph);  a1 = vmul(A1 * K1, ph);
            a2 = vmul(A2 * KS2, phf); a3 = vmul(A2 * KS3, phf);
            a4 = vmul(A1 * K4, ph);  a5 = vmul(A1 * K5, ph);
            a6 = vmul(A2 * KS6, phf); a7 = vmul(A2 * KS7, phf);
        } else {                 // pc == 0: regs 1,3,5,7 permuted
            a0 = vmul(A1 * K0, ph);  a1 = vmul(A2 * KS1, phf);
            a2 = vmul(A1 * K2, ph);  a3 = vmul(A2 * KS3, phf);
            a4 = vmul(A1 * K4, ph);  a5 = vmul(A2 * KS5, phf);
            a6 = vmul(A1 * K6, ph);  a7 = vmul(A2 * KS7, phf);
        }
    }

    // ---- conv layers; K-slot map {k0,k1,k2 | l0..l4} (R8/R9-verified) ----
    // init: {7,6,5 | 4,3,2,1,0}
    CONVM10(ws + 0);             // (6,7)
    SWKL0(0);                    // {4,6,5 | 7,3,2,1,0}
    CONVM02(ws + 16);            // (4,5)
    CONVM21(ws + 32);            // (5,6)
    SWKL2(2);                    // {4,6,2 | 7,3,5,1,0}
    SWKL1(1);                    // {4,3,2 | 7,6,5,1,0}
    CONVM21(ws + 48);            // (2,3)
    CONVM10(ws + 64);            // (3,4)
    SWKL0(3);                    // {1,3,2 | 7,6,5,4,0}
    SWKL1(4);                    // {1,0,2 | 7,6,5,4,3}
    CONVM10(ws + 80);            // (0,1)
    CONVM02(ws + 96);            // (1,2)
    // ---- layer 2 ----
    CONVM10(ws + 112);           // (0,1) + pool RY(q0) folded (hi)
    SWKL1(4);                    // {1,3,2 | 7,6,5,4,0}
    CONVM21(ws + 128);           // (2,3)
    CONVM02(ws + 144);           // (1,2) + pool RY(q2) folded (lo)
    SWKL0(3);                    // {4,3,2 | 7,6,5,1,0}
    SWKL2(2);                    // {4,3,5 | 7,6,2,1,0}
    CONVM02(ws + 160);           // (4,5)
    CONVM10(ws + 176);           // (3,4) + pool RY(q4) folded (lo)
    SWKL1(1);                    // {4,6,5 | 7,3,2,1,0}
    SWKL0(0);                    // {7,6,5 | 4,3,2,1,0}
    CONVM10(ws + 192);           // (6,7)
    CONVM21(ws + 208);           // (5,6) + pool RY(q6) folded (lo)
    // final layout: k0=q7,k1=q6,k2=q5 | l0=q4,l1=q3,l2=q2,l3=q1,l4=q0

    // ---- z: in-lane partials (q7,q6,q5) + WHT for lane qubits ----
    const float q0 = fmaf(a0.x, a0.x, a0.y * a0.y);
    const float q1 = fmaf(a1.x, a1.x, a1.y * a1.y);
    const float q2 = fmaf(a2.x, a2.x, a2.y * a2.y);
    const float q3 = fmaf(a3.x, a3.x, a3.y * a3.y);
    const float q4 = fmaf(a4.x, a4.x, a4.y * a4.y);
    const float q5 = fmaf(a5.x, a5.x, a5.y * a5.y);
    const float q6 = fmaf(a6.x, a6.x, a6.y * a6.y);
    const float q7 = fmaf(a7.x, a7.x, a7.y * a7.y);
    const float t0 = q0 + q1, t1 = q2 + q3, t2 = q4 + q5, t3 = q6 + q7;
    v2f z76;                                       // (zq7, zq6) partials
    z76.x = ((q0 - q1) + (q2 - q3)) + ((q4 - q5) + (q6 - q7));
    z76.y = (t0 - t1) + (t2 - t3);
    float z5p = (t0 + t1) - (t2 + t3);             // zq5 partial
    float w   = (t0 + t1) + (t2 + t3);             // psum -> WHT
    z76 += sx2<1>(z76);  z76 += sx2<2>(z76);  z76 += sx2<4>(z76);
    z76 += sx2<8>(z76);  z76 += sx2<16>(z76);
    z5p += sxc<1>(z5p);  z5p += sxc<2>(z5p);  z5p += sxc<4>(z5p);
    z5p += sxc<8>(z5p);  z5p += sxc<16>(z5p);
    w = whts<1>(w, lane); w = whts<2>(w, lane); w = whts<4>(w, lane);
    w = whts<8>(w, lane); w = whts<16>(w, lane);
    // lane-qubit z: q4@idx1, q3@idx2, q2@idx4, q1@idx8, q0@idx16 (per half)
    const int gb = (lane & 32) << 2;
    const float z4 = bperm(gb | (1 << 2),  w);
    const float z3 = bperm(gb | (2 << 2),  w);
    const float z2 = bperm(gb | (4 << 2),  w);
    const float z1 = bperm(gb | (8 << 2),  w);
    const float z0 = bperm(gb | (16 << 2), w);
    v4f zlo; zlo.x = z0; zlo.y = z1;  zlo.z = z2;    zlo.w = z3;
    v4f zhi; zhi.x = z4; zhi.y = z5p; zhi.z = z76.y; zhi.w = z76.x;

    // ---- MLP head: 8 -> 64 (relu) -> 32 (relu) -> 1; lane = rows hl, hl+32 --
    const v4f* r0 = (const v4f*)(w1 + hl * 8);
    const v4f* r1 = (const v4f*)(w1 + (hl + 32) * 8);
    v4f ha = zlo * r0[0]; ha = __builtin_elementwise_fma(zhi, r0[1], ha);
    v4f hb = zlo * r1[0]; hb = __builtin_elementwise_fma(zhi, r1[1], hb);
    const float h1a = fmaxf(b1[hl]      + (ha.x + ha.y) + (ha.z + ha.w), 0.0f);
    const float h1b = fmaxf(b1[hl + 32] + (hb.x + hb.y) + (hb.z + hb.w), 0.0f);

    __shared__ float h1s[4][2][64];          // wave-local; no barrier needed
    h1s[wv][half][hl]      = h1a;
    h1s[wv][half][hl + 32] = h1b;

    const v4f* hv  = (const v4f*)(&h1s[wv][half][0]);
    const v4f* w2r = (const v4f*)(w2 + hl * 64);
    v4f acc = {0.0f, 0.0f, 0.0f, 0.0f};
#pragma unroll
    for (int j = 0; j < 16; j++)
        acc = __builtin_elementwise_fma(hv[j], w2r[j], acc);
    const float h2 = fmaxf(b2[hl] + (acc.x + acc.y) + (acc.z + acc.w), 0.0f);

    float o = h2 * w3[hl];
    o += sxc<1>(o); o += sxc<2>(o); o += sxc<4>(o); o += sxc<8>(o); o += sxc<16>(o);

    if (hl == 0) out[g] = o + b3[0];
}

extern "C" void kernel_launch(void* const* d_in, const int* in_sizes, int n_in,
                              void* d_out, int out_size, void* d_ws, size_t ws_size,
                              hipStream_t stream) {
    const float* x      = (const float*)d_in[0];
    const float* adj    = (const float*)d_in[1];
    const float* w_proj = (const float*)d_in[2];
    const float* b_proj = (const float*)d_in[3];
    const float* qp     = (const float*)d_in[4];
    const float* w1     = (const float*)d_in[5];
    const float* b1     = (const float*)d_in[6];
    const float* w2     = (const float*)d_in[7];
    const float* b2     = (const float*)d_in[8];
    const float* w3     = (const float*)d_in[9];
    const float* b3     = (const float*)d_in[10];
    float* out = (float*)d_out;
    float* ws  = (float*)d_ws;                 // 256 + 13248*24 floats ~ 1.27 MB

    hipLaunchKernelGGL(prep_kernel, dim3(53), dim3(256), 0, stream,
                       x, adj, w_proj, b_proj, qp, ws);
    hipLaunchKernelGGL(qcnn_kernel, dim3(NPAIR / 4), dim3(256), 0, stream,
                       ws, w1, b1, w2, b2, w3, b3, out);
}

// Round 13
// 98.873 us; speedup vs baseline: 1.0007x; 1.0007x over previous
//
#include <hip/hip_runtime.h>
#include <math.h>

#define DEV static __device__ __forceinline__

constexpr int SS = 12;
constexpr int NN = 207;
constexpr int NCIRC = 64 * NN;          // 13248 circuits
constexpr int NPAIR = NCIRC / 2;        // 6624 waves; circuit A = lanes 0-31, B = lanes 32-63
// pair (g, g+6624): same node -> shared adjacency mask, conv matrices,
// w1/w2 rows; both circuits share ONE instruction stream.

// Layout: 32 lanes/circuit, 8 amps/lane (NAMED v2f a0..a7, re/im packed).
// Amp bits 0,1,2 = in-lane "K slots"; amp bits 3..7 = lane bits 0..4;
// lane bit 5 = circuit selector. Qubit q starts at amp bit (7-q).
//
// HARD RULE (R2/R3 LDS-demotion, R8 scratch-spill): state must be NAMED
// SCALARS; runtime permutes via wave-uniform switch over named temps.
// R13 = R11 (best measured: adjacency via bperm gather -- R12's analytic
// fold regressed) + z-broadcast via v_readlane (compile-time lane indices
// per half) instead of 5 runtime-address bpermutes.

typedef float v2f __attribute__((ext_vector_type(2)));
typedef float v4f __attribute__((ext_vector_type(4)));

DEV v2f splat2(float x) { v2f r; r.x = x; r.y = x; return r; }
DEV v2f vfma(float m, v2f a, v2f acc) { return __builtin_elementwise_fma(splat2(m), a, acc); }
DEV v2f vmul(float m, v2f a) { return splat2(m) * a; }
template<int M> DEV float sxc(float v) { return __shfl_xor(v, M, 64); }
template<int M> DEV v2f sx2(v2f v) { v2f r; r.x = sxc<M>(v.x); r.y = sxc<M>(v.y); return r; }
DEV float bperm(int addr, float v) {
    return __int_as_float(__builtin_amdgcn_ds_bpermute(addr, __float_as_int(v)));
}
DEV float rdl(float v, int l) {
    return __int_as_float(__builtin_amdgcn_readlane(__float_as_int(v), l));
}

// real 4x4 matrix on 4 named slots (basis order b00,b01,b10,b11)
#define CONV4(P, x00, x01, x10, x11) do {                                  \
    v2f _b00 = x00, _b01 = x01, _b10 = x10, _b11 = x11;                    \
    x00 = vfma((P)[0],  _b00, vfma((P)[1],  _b01, vfma((P)[2],  _b10, vmul((P)[3],  _b11)))); \
    x01 = vfma((P)[4],  _b00, vfma((P)[5],  _b01, vfma((P)[6],  _b10, vmul((P)[7],  _b11)))); \
    x10 = vfma((P)[8],  _b00, vfma((P)[9],  _b01, vfma((P)[10], _b10, vmul((P)[11], _b11)))); \
    x11 = vfma((P)[12], _b00, vfma((P)[13], _b01, vfma((P)[14], _b10, vmul((P)[15], _b11)))); \
} while (0)

// conv on K bits; CONVM10 hi=k1,lo=k0; CONVM02 hi=k0,lo=k2; CONVM21 hi=k2,lo=k1
#define CONVM10(P) do { CONV4(P, a0, a1, a2, a3); CONV4(P, a4, a5, a6, a7); } while (0)
#define CONVM02(P) do { CONV4(P, a0, a4, a1, a5); CONV4(P, a2, a6, a3, a7); } while (0)
#define CONVM21(P) do { CONV4(P, a0, a2, a4, a6); CONV4(P, a1, a3, a5, a7); } while (0)

// half-shuffle swap of one (lo,hi) slot pair across lane bit LB
#define SWP(ML, lb, lo, hi) do {                                           \
    v2f _u = (lb) ? lo : hi;                                               \
    v2f _v = sx2<ML>(_u);                                                  \
    lo = (lb) ? _v : lo;                                                   \
    hi = (lb) ? hi : _v;                                                   \
} while (0)

#define SWKL0(LB) do { const bool _lb = (lane >> (LB)) & 1;                \
    SWP(1 << (LB), _lb, a0, a1); SWP(1 << (LB), _lb, a2, a3);              \
    SWP(1 << (LB), _lb, a4, a5); SWP(1 << (LB), _lb, a6, a7); } while (0)
#define SWKL1(LB) do { const bool _lb = (lane >> (LB)) & 1;                \
    SWP(1 << (LB), _lb, a0, a2); SWP(1 << (LB), _lb, a1, a3);              \
    SWP(1 << (LB), _lb, a4, a6); SWP(1 << (LB), _lb, a5, a7); } while (0)
#define SWKL2(LB) do { const bool _lb = (lane >> (LB)) & 1;                \
    SWP(1 << (LB), _lb, a0, a4); SWP(1 << (LB), _lb, a1, a5);              \
    SWP(1 << (LB), _lb, a2, a6); SWP(1 << (LB), _lb, a3, a7); } while (0)

// WHT butterfly stage (R7-verified)
template<int MK> DEV float whts(float p, int lane) {
    float t = sxc<MK>(p);
    return (lane & MK) ? (t - p) : (p + t);
}

// ---- prep kernel: blocks 0..51 = per-circuit front-end; block 52 = matrices
// + adjacency masks (identical to R11, verified). ----
__global__ void prep_kernel(const float* __restrict__ x, const float* __restrict__ adj,
                            const float* __restrict__ w_proj, const float* __restrict__ b_proj,
                            const float* __restrict__ qp, float* __restrict__ ws) {
    if (blockIdx.x < 52) {
        const int t = blockIdx.x * 256 + threadIdx.x;
        if (t >= NCIRC) return;
        const int b = t / NN, node = t - b * NN;
        const float* xp = x + ((size_t)b * SS * NN + node) * 2;
        v2f av0 = splat2(0.0f), av1 = av0, av2 = av0, av3 = av0,
            av4 = av0, av5 = av0, av6 = av0, av7 = av0;
#pragma unroll
        for (int s = 0; s < SS; s++) {
            const v2f xv = *(const v2f*)(xp + (size_t)s * (NN * 2));
            const float* wp = w_proj + 2 * s;
            av0 = __builtin_elementwise_fma(xv, *(const v2f*)(wp + 0 * 24), av0);
            av1 = __builtin_elementwise_fma(xv, *(const v2f*)(wp + 1 * 24), av1);
            av2 = __builtin_elementwise_fma(xv, *(const v2f*)(wp + 2 * 24), av2);
            av3 = __builtin_elementwise_fma(xv, *(const v2f*)(wp + 3 * 24), av3);
            av4 = __builtin_elementwise_fma(xv, *(const v2f*)(wp + 4 * 24), av4);
            av5 = __builtin_elementwise_fma(xv, *(const v2f*)(wp + 5 * 24), av5);
            av6 = __builtin_elementwise_fma(xv, *(const v2f*)(wp + 6 * 24), av6);
            av7 = __builtin_elementwise_fma(xv, *(const v2f*)(wp + 7 * 24), av7);
        }
        const float PI_F = 3.14159265358979323846f;
        const float ang0 = fminf(fmaxf(av0.x + av0.y + b_proj[0], -PI_F), PI_F);
        const float ang1 = fminf(fmaxf(av1.x + av1.y + b_proj[1], -PI_F), PI_F);
        const float ang2 = fminf(fmaxf(av2.x + av2.y + b_proj[2], -PI_F), PI_F);
        const float ang3 = fminf(fmaxf(av3.x + av3.y + b_proj[3], -PI_F), PI_F);
        const float ang4 = fminf(fmaxf(av4.x + av4.y + b_proj[4], -PI_F), PI_F);
        const float ang5 = fminf(fmaxf(av5.x + av5.y + b_proj[5], -PI_F), PI_F);
        const float ang6 = fminf(fmaxf(av6.x + av6.y + b_proj[6], -PI_F), PI_F);
        const float ang7 = fminf(fmaxf(av7.x + av7.y + b_proj[7], -PI_F), PI_F);
        float c0,s0,c1,s1,c2,s2,c3,s3,c4,s4,c5,s5,c6,s6,c7,s7;
        __sincosf(0.5f * ang0, &s0, &c0); __sincosf(0.5f * ang1, &s1, &c1);
        __sincosf(0.5f * ang2, &s2, &c2); __sincosf(0.5f * ang3, &s3, &c3);
        __sincosf(0.5f * ang4, &s4, &c4); __sincosf(0.5f * ang5, &s5, &c5);
        __sincosf(0.5f * ang6, &s6, &c6); __sincosf(0.5f * ang7, &s7, &c7);
        float* dst = ws + 256 + (size_t)t * 24;
        dst[0] = c0;  dst[1] = c1;  dst[2] = c2;  dst[3] = c3;
        dst[4] = c4;  dst[5] = c5;  dst[6] = c6;  dst[7] = c7;
        dst[8] = s0;  dst[9] = s1;  dst[10] = s2; dst[11] = s3;
        dst[12] = s4; dst[13] = s5; dst[14] = s6; dst[15] = s7;
        dst[16] = ang4; dst[17] = ang5; dst[18] = ang6; dst[19] = ang7;
        return;
    }
    // ---- block 52: adjacency masks + fused conv matrices ----
    const int n = threadIdx.x;
    if (n >= 14 && n < 64 + 14) {
        const int cq = n - 14;
        if (cq < 8) {
            int M = 0;
            for (int t = 0; t < 8; t++) {
                if (t != cq && adj[cq * NN + t] > 0.0f) M |= 1 << (7 - t);
            }
            ((int*)ws)[224 + cq] = M;
        }
        return;
    }
    if (n >= 14) return;
    // schedule: L1 (6,7)(4,5)(5,6)(2,3)(3,4)(0,1)(1,2); L2 (0,1)(2,3)(1,2)(4,5)(3,4)(6,7)(5,6)
    const int Jt[14] = {12, 8, 24, 4, 20, 0, 16, 28, 32, 44, 36, 48, 40, 52};
    const int J = Jt[n];
    float cg[4], sg[4];
    for (int i = 0; i < 4; i++) sincosf(0.5f * qp[J + i], &sg[i], &cg[i]);
    float A[16], B[16], M[16];
    {
        float H[2][2] = {{cg[0], -sg[0]}, {sg[0], cg[0]}};
        float L[2][2] = {{cg[1], -sg[1]}, {sg[1], cg[1]}};
        for (int a_ = 0; a_ < 2; a_++) for (int b_ = 0; b_ < 2; b_++)
            for (int p = 0; p < 2; p++) for (int q = 0; q < 2; q++)
                A[(2*a_+b_)*4 + (2*p+q)] = H[a_][p] * L[b_][q];
    }
    for (int j = 0; j < 4; j++) { float t = A[8+j]; A[8+j] = A[12+j]; A[12+j] = t; }  // CNOT hi->lo
    {
        float H[2][2] = {{cg[2], -sg[2]}, {sg[2], cg[2]}};
        float L[2][2] = {{cg[3], -sg[3]}, {sg[3], cg[3]}};
        for (int a_ = 0; a_ < 2; a_++) for (int b_ = 0; b_ < 2; b_++)
            for (int p = 0; p < 2; p++) for (int q = 0; q < 2; q++)
                B[(2*a_+b_)*4 + (2*p+q)] = H[a_][p] * L[b_][q];
    }
    for (int r = 0; r < 4; r++)
        for (int c = 0; c < 4; c++) {
            float acc = 0.0f;
            for (int k = 0; k < 4; k++) acc += B[r*4+k] * A[k*4+c];
            M[r*4+c] = acc;
        }
    for (int j = 0; j < 4; j++) { float t = M[4+j]; M[4+j] = M[12+j]; M[12+j] = t; }  // CNOT lo->hi
    // fold pool RYs (left-multiply; applied AFTER the conv) — R10-verified
    int mode = 0; float fc = 1.0f, fs = 0.0f;
    if (n == 7)  { sincosf(0.5f * qp[56], &fs, &fc); mode = 2; }   // RY(q0) on hi
    if (n == 9)  { sincosf(0.5f * qp[58], &fs, &fc); mode = 1; }   // RY(q2) on lo
    if (n == 11) { sincosf(0.5f * qp[60], &fs, &fc); mode = 1; }   // RY(q4) on lo
    if (n == 13) { sincosf(0.5f * qp[62], &fs, &fc); mode = 1; }   // RY(q6) on lo
    if (mode == 1) {
        for (int j = 0; j < 4; j++) {
            float r0 = M[j],     r1 = M[4+j];
            M[j]    = fc * r0 - fs * r1;  M[4+j]  = fs * r0 + fc * r1;
            float r2 = M[8+j],   r3 = M[12+j];
            M[8+j]  = fc * r2 - fs * r3;  M[12+j] = fs * r2 + fc * r3;
        }
    } else if (mode == 2) {
        for (int j = 0; j < 4; j++) {
            float r0 = M[j],     r2 = M[8+j];
            M[j]    = fc * r0 - fs * r2;  M[8+j]  = fs * r0 + fc * r2;
            float r1 = M[4+j],   r3 = M[12+j];
            M[4+j]  = fc * r1 - fs * r3;  M[12+j] = fs * r1 + fc * r3;
        }
    }
    for (int i = 0; i < 16; i++) ws[16*n + i] = M[i];
}

__global__ __launch_bounds__(256, 7) void qcnn_kernel(
    const float* __restrict__ ws,
    const float* __restrict__ w1, const float* __restrict__ b1,
    const float* __restrict__ w2, const float* __restrict__ b2,
    const float* __restrict__ w3, const float* __restrict__ b3,
    float* __restrict__ out)
{
    const int lane = threadIdx.x & 63;
    const int half = lane >> 5;                  // 0 = circuit A, 1 = circuit B
    const int hl   = lane & 31;
    const int wv   = threadIdx.x >> 6;
    const int gA   = blockIdx.x * 4 + wv;        // grid exact: 1656*4 == 6624
    const int bA   = gA / NN;
    const int node = gA - bA * NN;
    const int g    = gA + half * NPAIR;          // this half's circuit id

    // ---- load precomputed per-circuit trig (broadcast within each half) ----
    const float* cd = ws + 256 + (size_t)g * 24;
    const v4f cA = *(const v4f*)(cd + 0);        // c0..c3
    const v4f cB = *(const v4f*)(cd + 4);        // c4..c7
    const v4f sA = *(const v4f*)(cd + 8);        // s0..s3
    const v4f sB = *(const v4f*)(cd + 12);       // s4..s7
    const v4f rz = *(const v4f*)(cd + 16);       // clipped ang4..ang7

    // qubits 0..4 -> lane bits 4..0
    const float A = (((lane >> 4) & 1) ? sA.x : cA.x) * (((lane >> 3) & 1) ? sA.y : cA.y)
                  * (((lane >> 2) & 1) ? sA.z : cA.z) * (((lane >> 1) & 1) ? sA.w : cA.w)
                  * (((lane >> 0) & 1) ? sB.x : cB.x);
    // RZ phase: qubits 0..3 -> lane bits 4..1
    const float phi = (((lane >> 4) & 1) ? 0.5f : -0.5f) * rz.x
                    + (((lane >> 3) & 1) ? 0.5f : -0.5f) * rz.y
                    + (((lane >> 2) & 1) ? 0.5f : -0.5f) * rz.z
                    + (((lane >> 1) & 1) ? 0.5f : -0.5f) * rz.w;
    float cp, sp;
    __sincosf(phi, &sp, &cp);
    v2f ph; ph.x = cp; ph.y = sp;

    // amp bit0=q7, bit1=q6, bit2=q5
    const float c5c6 = cB.y * cB.z, c5s6 = cB.y * sB.z;
    const float s5c6 = sB.y * cB.z, s5s6 = sB.y * sB.z;
    v2f a0 = vmul(A * c5c6 * cB.w, ph), a1 = vmul(A * c5c6 * sB.w, ph);
    v2f a2 = vmul(A * c5s6 * cB.w, ph), a3 = vmul(A * c5s6 * sB.w, ph);
    v2f a4 = vmul(A * s5c6 * cB.w, ph), a5 = vmul(A * s5c6 * sB.w, ph);
    v2f a6 = vmul(A * s5s6 * cB.w, ph), a7 = vmul(A * s5s6 * sB.w, ph);

    // ---- adjacency permutation: mask precomputed in prep (R11-verified) ----
    const int cq = node & 7;
    const int M = ((const int*)ws)[224 + cq];
    if (M) {
        const int Mlo = M & 7;               // in-lane amp bits
        const int Mhi = (M >> 3) & 31;       // lane bits (stays within half)
        v2f p0, p1, p2, p3, p4, p5, p6, p7;
        switch (Mlo) {                       // wave-uniform; p_k = a_(k^Mlo)
        case 0: p0=a0;p1=a1;p2=a2;p3=a3;p4=a4;p5=a5;p6=a6;p7=a7; break;
        case 1: p0=a1;p1=a0;p2=a3;p3=a2;p4=a5;p5=a4;p6=a7;p7=a6; break;
        case 2: p0=a2;p1=a3;p2=a0;p3=a1;p4=a6;p5=a7;p6=a4;p7=a5; break;
        case 3: p0=a3;p1=a2;p2=a1;p3=a0;p4=a7;p5=a6;p6=a5;p7=a4; break;
        case 4: p0=a4;p1=a5;p2=a6;p3=a7;p4=a0;p5=a1;p6=a2;p7=a3; break;
        case 5: p0=a5;p1=a4;p2=a7;p3=a6;p4=a1;p5=a0;p6=a3;p7=a2; break;
        case 6: p0=a6;p1=a7;p2=a4;p3=a5;p4=a2;p5=a3;p6=a0;p7=a1; break;
        default:p0=a7;p1=a6;p2=a5;p3=a4;p4=a3;p5=a2;p6=a1;p7=a0; break;
        }
        const int addr = (lane ^ Mhi) << 2;  // Mhi<32 -> half-preserving
        p0.x = bperm(addr, p0.x); p0.y = bperm(addr, p0.y);
        p1.x = bperm(addr, p1.x); p1.y = bperm(addr, p1.y);
        p2.x = bperm(addr, p2.x); p2.y = bperm(addr, p2.y);
        p3.x = bperm(addr, p3.x); p3.y = bperm(addr, p3.y);
        p4.x = bperm(addr, p4.x); p4.y = bperm(addr, p4.y);
        p5.x = bperm(addr, p5.x); p5.y = bperm(addr, p5.y);
        p6.x = bperm(addr, p6.x); p6.y = bperm(addr, p6.y);
        p7.x = bperm(addr, p7.x); p7.y = bperm(addr, p7.y);
        const int pc = 7 - cq;               // control amplitude bit (uniform)
        if (pc >= 3) {
            const bool bs = (lane >> (pc - 3)) & 1;
            a0 = bs ? p0 : a0; a1 = bs ? p1 : a1; a2 = bs ? p2 : a2; a3 = bs ? p3 : a3;
            a4 = bs ? p4 : a4; a5 = bs ? p5 : a5; a6 = bs ? p6 : a6; a7 = bs ? p7 : a7;
        } else if (pc == 2) { a4 = p4; a5 = p5; a6 = p6; a7 = p7; }
        else if (pc == 1)   { a2 = p2; a3 = p3; a6 = p6; a7 = p7; }
        else                { a1 = p1; a3 = p3; a5 = p5; a7 = p7; }
    }

    // ---- conv layers; K-slot map {k0,k1,k2 | l0..l4} (R8/R9-verified) ----
    // init: {7,6,5 | 4,3,2,1,0}
    CONVM10(ws + 0);             // (6,7)
    SWKL0(0);                    // {4,6,5 | 7,3,2,1,0}
    CONVM02(ws + 16);            // (4,5)
    CONVM21(ws + 32);            // (5,6)
    SWKL2(2);                    // {4,6,2 | 7,3,5,1,0}
    SWKL1(1);                    // {4,3,2 | 7,6,5,1,0}
    CONVM21(ws + 48);            // (2,3)
    CONVM10(ws + 64);            // (3,4)
    SWKL0(3);                    // {1,3,2 | 7,6,5,4,0}
    SWKL1(4);                    // {1,0,2 | 7,6,5,4,3}
    CONVM10(ws + 80);            // (0,1)
    CONVM02(ws + 96);            // (1,2)
    // ---- layer 2 ----
    CONVM10(ws + 112);           // (0,1) + pool RY(q0) folded (hi)
    SWKL1(4);                    // {1,3,2 | 7,6,5,4,0}
    CONVM21(ws + 128);           // (2,3)
    CONVM02(ws + 144);           // (1,2) + pool RY(q2) folded (lo)
    SWKL0(3);                    // {4,3,2 | 7,6,5,1,0}
    SWKL2(2);                    // {4,3,5 | 7,6,2,1,0}
    CONVM02(ws + 160);           // (4,5)
    CONVM10(ws + 176);           // (3,4) + pool RY(q4) folded (lo)
    SWKL1(1);                    // {4,6,5 | 7,3,2,1,0}
    SWKL0(0);                    // {7,6,5 | 4,3,2,1,0}
    CONVM10(ws + 192);           // (6,7)
    CONVM21(ws + 208);           // (5,6) + pool RY(q6) folded (lo)
    // final layout: k0=q7,k1=q6,k2=q5 | l0=q4,l1=q3,l2=q2,l3=q1,l4=q0

    // ---- z: in-lane partials (q7,q6,q5) + WHT for lane qubits ----
    const float q0 = fmaf(a0.x, a0.x, a0.y * a0.y);
    const float q1 = fmaf(a1.x, a1.x, a1.y * a1.y);
    const float q2 = fmaf(a2.x, a2.x, a2.y * a2.y);
    const float q3 = fmaf(a3.x, a3.x, a3.y * a3.y);
    const float q4 = fmaf(a4.x, a4.x, a4.y * a4.y);
    const float q5 = fmaf(a5.x, a5.x, a5.y * a5.y);
    const float q6 = fmaf(a6.x, a6.x, a6.y * a6.y);
    const float q7 = fmaf(a7.x, a7.x, a7.y * a7.y);
    const float t0 = q0 + q1, t1 = q2 + q3, t2 = q4 + q5, t3 = q6 + q7;
    v2f z76;                                       // (zq7, zq6) partials
    z76.x = ((q0 - q1) + (q2 - q3)) + ((q4 - q5) + (q6 - q7));
    z76.y = (t0 - t1) + (t2 - t3);
    float z5p = (t0 + t1) - (t2 + t3);             // zq5 partial
    float w   = (t0 + t1) + (t2 + t3);             // psum -> WHT
    z76 += sx2<1>(z76);  z76 += sx2<2>(z76);  z76 += sx2<4>(z76);
    z76 += sx2<8>(z76);  z76 += sx2<16>(z76);
    z5p += sxc<1>(z5p);  z5p += sxc<2>(z5p);  z5p += sxc<4>(z5p);
    z5p += sxc<8>(z5p);  z5p += sxc<16>(z5p);
    w = whts<1>(w, lane); w = whts<2>(w, lane); w = whts<4>(w, lane);
    w = whts<8>(w, lane); w = whts<16>(w, lane);
    // lane-qubit z: WHT coeff at lane idx (per half): q4@1, q3@2, q2@4,
    // q1@8, q0@16. Indices are compile-time -> v_readlane pairs + select
    // (replaces 5 runtime-address bpermutes: zero ds-pipe, no lgkm stage).
    const float z4 = half ? rdl(w, 33) : rdl(w, 1);
    const float z3 = half ? rdl(w, 34) : rdl(w, 2);
    const float z2 = half ? rdl(w, 36) : rdl(w, 4);
    const float z1 = half ? rdl(w, 40) : rdl(w, 8);
    const float z0 = half ? rdl(w, 48) : rdl(w, 16);
    v4f zlo; zlo.x = z0; zlo.y = z1;  zlo.z = z2;    zlo.w = z3;
    v4f zhi; zhi.x = z4; zhi.y = z5p; zhi.z = z76.y; zhi.w = z76.x;

    // ---- MLP head: 8 -> 64 (relu) -> 32 (relu) -> 1; lane = rows hl, hl+32 --
    const v4f* r0 = (const v4f*)(w1 + hl * 8);
    const v4f* r1 = (const v4f*)(w1 + (hl + 32) * 8);
    v4f ha = zlo * r0[0]; ha = __builtin_elementwise_fma(zhi, r0[1], ha);
    v4f hb = zlo * r1[0]; hb = __builtin_elementwise_fma(zhi, r1[1], hb);
    const float h1a = fmaxf(b1[hl]      + (ha.x + ha.y) + (ha.z + ha.w), 0.0f);
    const float h1b = fmaxf(b1[hl + 32] + (hb.x + hb.y) + (hb.z + hb.w), 0.0f);

    __shared__ float h1s[4][2][64];          // wave-local; no barrier needed
    h1s[wv][half][hl]      = h1a;
    h1s[wv][half][hl + 32] = h1b;

    const v4f* hv  = (const v4f*)(&h1s[wv][half][0]);
    const v4f* w2r = (const v4f*)(w2 + hl * 64);
    v4f acc = {0.0f, 0.0f, 0.0f, 0.0f};
#pragma unroll
    for (int j = 0; j < 16; j++)
        acc = __builtin_elementwise_fma(hv[j], w2r[j], acc);
    const float h2 = fmaxf(b2[hl] + (acc.x + acc.y) + (acc.z + acc.w), 0.0f);

    float o = h2 * w3[hl];
    o += sxc<1>(o); o += sxc<2>(o); o += sxc<4>(o); o += sxc<8>(o); o += sxc<16>(o);

    if (hl == 0) out[g] = o + b3[0];
}

extern "C" void kernel_launch(void* const* d_in, const int* in_sizes, int n_in,
                              void* d_out, int out_size, void* d_ws, size_t ws_size,
                              hipStream_t stream) {
    const float* x      = (const float*)d_in[0];
    const float* adj    = (const float*)d_in[1];
    const float* w_proj = (const float*)d_in[2];
    const float* b_proj = (const float*)d_in[3];
    const float* qp     = (const float*)d_in[4];
    const float* w1     = (const float*)d_in[5];
    const float* b1     = (const float*)d_in[6];
    const float* w2     = (const float*)d_in[7];
    const float* b2     = (const float*)d_in[8];
    const float* w3     = (const float*)d_in[9];
    const float* b3     = (const float*)d_in[10];
    float* out = (float*)d_out;
    float* ws  = (float*)d_ws;                 // 256 + 13248*24 floats ~ 1.27 MB

    hipLaunchKernelGGL(prep_kernel, dim3(53), dim3(256), 0, stream,
                       x, adj, w_proj, b_proj, qp, ws);
    hipLaunchKernelGGL(qcnn_kernel, dim3(NPAIR / 4), dim3(256), 0, stream,
                       ws, w1, b1, w2, b2, w3, b3, out);
}